// Round 8
// baseline (156.068 us; speedup 1.0000x reference)
//
#include <hip/hip_runtime.h>
#include <math.h>

// Problem constants (fixed by reference setup_inputs)
#define BSZ 4096   // B
#define NROW 8192  // N = 2B
#define DIM 128    // D
#define LOG2E10 14.426950408889634f   // 10 / ln(2): exp(10x) = exp2(x * this)

typedef __attribute__((ext_vector_type(8))) short bf16x8;   // 8 bf16 = 4 VGPRs
typedef __attribute__((ext_vector_type(4))) float f32x4;    // MFMA acc

// ws layout (in floats):
//   pnh    [0, N*D/2)          normalized rows, bf16, LINEAR layout (2 MB)
//   pnh_sw [N*D/2, N*D)        same data, 16B-chunk j stored at j^(row&15)
//   g      [+256)              label-sum vectors g0,g1 (fp32)
//   cnt    [+2)                label counts in y2
//   spart  [+64*N)             partial exp row-sums, slice-major [slice*N+row]
//   part   [+2048)             per-block loss partials
#define PNH_F     (NROW * DIM / 2)
#define G_OFF     (2 * PNH_F)
#define CNT_OFF   (G_OFF + 256)
#define SPART_OFF (G_OFF + 512)
#define PART_OFF  (SPART_OFF + 64 * NROW)

__device__ __forceinline__ unsigned short f2bf(float f) {  // RNE
    unsigned u = __float_as_uint(f);
    return (unsigned short)((u + 0x7FFF + ((u >> 16) & 1)) >> 16);
}

// ------ Kernel 1: row normalization -> bf16 (wave per row) + zero g -------
__global__ void k_norm(const float* __restrict__ zi, const float* __restrict__ zj,
                       unsigned* __restrict__ pnh, unsigned* __restrict__ pnsw,
                       float* __restrict__ g) {
    int tid  = threadIdx.x;
    if (blockIdx.x == 0) g[tid] = 0.f;      // zero g before k_colsum's atomics
    int wave = tid >> 6, lane = tid & 63;
    int row  = blockIdx.x * 4 + wave;
    const float* src = (row < BSZ) ? (zi + (size_t)row * DIM)
                                   : (zj + (size_t)(row - BSZ) * DIM);
    float2 v = ((const float2*)src)[lane];
    float ss = v.x * v.x + v.y * v.y;
    #pragma unroll
    for (int m = 32; m; m >>= 1) ss += __shfl_xor(ss, m, 64);
    float inv = 1.0f / fmaxf(sqrtf(ss), 1e-8f);
    unsigned short h0 = f2bf(v.x * inv), h1 = f2bf(v.y * inv);
    unsigned pack = (unsigned)h0 | ((unsigned)h1 << 16);
    pnh[(size_t)row * 64 + lane] = pack;
    int j = lane >> 2;                       // 16B chunk index (4 uints each)
    int sw = ((j ^ (row & 15)) << 2) | (lane & 3);
    pnsw[(size_t)row * 64 + sw] = pack;
}

// ---- Kernel 2: label-sum vectors g0/g1, coalesced row-major + atomics ----
__global__ void k_colsum(const unsigned* __restrict__ pnh, const int* __restrict__ y,
                         float* __restrict__ g, float* __restrict__ cnt) {
    __shared__ float red[4][4][64];   // [rowgrp][{s0a,s0b,s1a,s1b}][d2]
    int tid = threadIdx.x;
    if (blockIdx.x < 128) {
        int d2 = tid & 63;            // uint index: holds d = 2*d2, 2*d2+1
        int rg = tid >> 6;            // 0..3
        int row0 = blockIdx.x * 64 + rg * 16;
        float s0a = 0.f, s0b = 0.f, s1a = 0.f, s1b = 0.f;
        #pragma unroll 4
        for (int i = 0; i < 16; ++i) {
            int r = row0 + i;
            unsigned u = pnh[(size_t)r * 64 + d2];
            float va = __uint_as_float(u << 16);
            float vb = __uint_as_float(u & 0xFFFF0000u);
            if (y[r & (BSZ - 1)]) { s1a += va; s1b += vb; }
            else                  { s0a += va; s0b += vb; }
        }
        red[rg][0][d2] = s0a; red[rg][1][d2] = s0b;
        red[rg][2][d2] = s1a; red[rg][3][d2] = s1b;
        __syncthreads();
        int lab = tid >> 7, d = tid & 127;
        int which = lab * 2 + (d & 1), dd2 = d >> 1;
        float s = red[0][which][dd2] + red[1][which][dd2]
                + red[2][which][dd2] + red[3][which][dd2];
        atomicAdd(&g[lab * DIM + d], s);
    } else {
        __shared__ float r0[256];
        float c = 0.f;
        for (int r = tid; r < BSZ; r += 256) c += (float)y[r];
        r0[tid] = c;
        __syncthreads();
        for (int s = 128; s; s >>= 1) {
            if (tid < s) r0[tid] += r0[tid + s];
            __syncthreads();
        }
        if (tid == 0) { cnt[1] = 2.0f * r0[0]; cnt[0] = (float)NROW - 2.0f * r0[0]; }
    }
}

// ---- Kernel 3: bf16 MFMA GEMM + exp + row-sum — LDS-FREE, BARRIER-FREE ---
// Round-7 lesson: 32KB-LDS blocks with a barrier prologue gave only ~2-3
// resident blocks and per-block startup bubbles (MfmaUtil 13%). This round:
// NO LDS tile, NO __syncthreads — A and B fragments both load straight from
// the pre-swizzled pnsw (every load = coalesced 1KB/wave burst; B's 2MB is
// L2-resident). Occupancy is VGPR-limited only (~16 waves/CU).
// Work: wave = 64 rows x 128 cols = 8 independent col-16 tiles
//   (4 B-loads + 16 MFMA + 16 exp each; compiler pipelines across tiles).
// Grid 2048 = 128 rowgroups (fastest -> XCD A-locality) x 16 colgroups.
// Aggregate L2 read traffic ~384 MB @ 34.5 TB/s ~ 11 us = expected bound.
// Epilogue: wave-private LDS transpose (no barrier) -> ONE coalesced 256B
// store per wave (round-7's 4-lane scattered stores amplified to 39MB HBM).
__global__ __launch_bounds__(256, 4)
void k_expsum(const unsigned short* __restrict__ pnsw, float* __restrict__ spart) {
    __shared__ float xpose[4][64];           // 1 KB wave-private scratch
    int tid  = threadIdx.x;
    int lane = tid & 63;
    int w    = tid >> 6;
    int l15 = lane & 15, q = lane >> 4;
    int bid = blockIdx.x;
    int rg  = bid & 127;                     // rowgroup fastest: XCD r gets
    int cg  = bid >> 7;                      // rg = r (mod 8) -> A stays in L2
    int rwb = rg * 64;                       // this wave's 64 rows
    int cb0 = cg * 512 + w * 128;            // this wave's 128 cols

    // A fragments: 16 coalesced global loads, held for the whole kernel
    bf16x8 a[4][4];
    #pragma unroll
    for (int rf = 0; rf < 4; ++rf) {
        const unsigned short* ab = pnsw + (size_t)(rwb + rf * 16 + l15) * DIM;
        #pragma unroll
        for (int ks = 0; ks < 4; ++ks)
            a[rf][ks] = *(const bf16x8*)(ab + (((ks * 4 + q) ^ l15) << 3));
    }

    float rs[4][4];
    #pragma unroll
    for (int rf = 0; rf < 4; ++rf)
        #pragma unroll
        for (int e = 0; e < 4; ++e) rs[rf][e] = 0.f;

    #pragma unroll
    for (int t = 0; t < 8; ++t) {            // 8 independent col-16 tiles
        int cb = cb0 + t * 16;
        // B fragments straight from L2 (coalesced 1KB bursts, swizzled src)
        bf16x8 b[4];
        const unsigned short* bb = pnsw + (size_t)(cb + l15) * DIM;
        #pragma unroll
        for (int ks = 0; ks < 4; ++ks)
            b[ks] = *(const bf16x8*)(bb + (((ks * 4 + q) ^ l15) << 3));

        f32x4 acc[4];
        #pragma unroll
        for (int rf = 0; rf < 4; ++rf) acc[rf] = (f32x4){0.f, 0.f, 0.f, 0.f};
        #pragma unroll
        for (int ks = 0; ks < 4; ++ks)
            #pragma unroll
            for (int rf = 0; rf < 4; ++rf)
                acc[rf] = __builtin_amdgcn_mfma_f32_16x16x32_bf16(a[rf][ks], b[ks], acc[rf], 0, 0, 0);

        // exp(10*sim); diagonal masking only where the 16-col window
        // overlaps this wave's 64 rows (wave-uniform predicate)
        bool dia = ((unsigned)(cb - rwb) < 64u);
        if (dia) {
            int col = cb + l15;
            #pragma unroll
            for (int rf = 0; rf < 4; ++rf)
                #pragma unroll
                for (int e = 0; e < 4; ++e) {
                    int row = rwb + rf * 16 + q * 4 + e;   // C-layout row
                    float ex = exp2f(acc[rf][e] * LOG2E10);
                    if (row == col) ex = 0.f;
                    rs[rf][e] += ex;
                }
        } else {
            #pragma unroll
            for (int rf = 0; rf < 4; ++rf)
                #pragma unroll
                for (int e = 0; e < 4; ++e)
                    rs[rf][e] += exp2f(acc[rf][e] * LOG2E10);
        }
    }

    // cross-lane reduce over the 16 l15 lanes, then wave-private LDS
    // transpose (same-wave DS ops are ordered; no barrier) -> one coalesced
    // 256 B store per wave into this wave's private slice run.
    #pragma unroll
    for (int rf = 0; rf < 4; ++rf)
        #pragma unroll
        for (int e = 0; e < 4; ++e) {
            float v = rs[rf][e];
            v += __shfl_xor(v, 1, 16);
            v += __shfl_xor(v, 2, 16);
            v += __shfl_xor(v, 4, 16);
            v += __shfl_xor(v, 8, 16);
            if (l15 == 0) xpose[w][rf * 16 + q * 4 + e] = v;
        }
    int slice = cg * 4 + w;                  // 64 slices, block-private runs
    spart[(size_t)slice * NROW + rwb + lane] = xpose[w][lane];
}

// ------------- Kernel 4: per-row finalize (wave per row, 2048 blocks) ------
__global__ void k_finalize(const unsigned* __restrict__ pnh, const float* __restrict__ spart,
                           const float* __restrict__ g, const float* __restrict__ cnt,
                           const int* __restrict__ y, float* __restrict__ partial) {
    __shared__ float red[4];
    int tid = threadIdx.x, wv = tid >> 6, lane = tid & 63;
    int row = blockIdx.x * 4 + wv;
    int lab = y[row & (BSZ - 1)];
    unsigned u = pnh[(size_t)row * 64 + lane];
    float p0 = __uint_as_float(u << 16);
    float p1 = __uint_as_float(u & 0xFFFF0000u);
    float2 gv = ((const float2*)(g + lab * DIM))[lane];
    float dg = p0 * gv.x + p1 * gv.y;
    float ds = p0 * p0 + p1 * p1;
    float sp = spart[(size_t)lane * NROW + row];   // lane = slice (L2-resident)
    #pragma unroll
    for (int m = 32; m; m >>= 1) {
        dg += __shfl_xor(dg, m, 64);
        ds += __shfl_xor(ds, m, 64);
        sp += __shfl_xor(sp, m, 64);
    }
    if (lane == 0) {
        float C = cnt[lab] - 1.0f;           // pos count excludes self
        float P = (dg - ds) * 10.0f;         // sum of sims over positives
        red[wv] = logf(sp) - P / C;          // -(mean log prob pos)
    }
    __syncthreads();
    if (tid == 0) partial[blockIdx.x] = red[0] + red[1] + red[2] + red[3];
}

// --------------------- Kernel 5: final reduce of 2048 ----------------------
__global__ void k_sum(const float* __restrict__ partial, float* __restrict__ out) {
    __shared__ float red[256];
    float v = 0.f;
    #pragma unroll
    for (int i = 0; i < 8; ++i) v += partial[threadIdx.x + 256 * i];
    red[threadIdx.x] = v;
    __syncthreads();
    for (int s = 128; s; s >>= 1) {
        if (threadIdx.x < s) red[threadIdx.x] += red[threadIdx.x + s];
        __syncthreads();
    }
    if (threadIdx.x == 0) out[0] = red[0];
}

extern "C" void kernel_launch(void* const* d_in, const int* in_sizes, int n_in,
                              void* d_out, int out_size, void* d_ws, size_t ws_size,
                              hipStream_t stream) {
    const float* zi = (const float*)d_in[0];
    const float* zj = (const float*)d_in[1];
    const int*   y  = (const int*)d_in[2];
    float* out = (float*)d_out;
    float* ws  = (float*)d_ws;

    unsigned* pnh   = (unsigned*)ws;                 // N*64 uints (linear)
    unsigned* pnsw  = (unsigned*)(ws + PNH_F);       // N*64 uints (swizzled)
    float* g       = ws + G_OFF;
    float* cnt     = ws + CNT_OFF;
    float* spart   = ws + SPART_OFF;
    float* partial = ws + PART_OFF;

    k_norm<<<NROW / 4, 256, 0, stream>>>(zi, zj, pnh, pnsw, g);
    k_colsum<<<129, 256, 0, stream>>>(pnh, y, g, cnt);
    k_expsum<<<2048, 256, 0, stream>>>((const unsigned short*)pnsw, spart);
    k_finalize<<<NROW / 4, 256, 0, stream>>>(pnh, spart, g, cnt, y, partial);
    k_sum<<<1, 256, 0, stream>>>(partial, out);
}

// Round 9
// 100.688 us; speedup vs baseline: 1.5500x; 1.5500x over previous
//
#include <hip/hip_runtime.h>
#include <math.h>

// Problem constants (fixed by reference setup_inputs)
#define BSZ 4096   // B
#define NROW 8192  // N = 2B
#define DIM 128    // D
#define LOG2E10 14.426950408889634f   // 10 / ln(2): exp(10x) = exp2(x * this)

typedef __attribute__((ext_vector_type(8))) short bf16x8;   // 8 bf16 = 4 VGPRs
typedef __attribute__((ext_vector_type(4))) float f32x4;    // MFMA acc

// ws layout (in floats):
//   pnh    [0, N*D/2)          normalized rows, bf16, LINEAR (2 MB)
//   pnswB  [+N*D/2)            swizzled copy (16B chunk j at j^(row&15))
//   pnswA  [+N*D/2)            swizzled copy PRE-SCALED by 10/ln2 (A side)
//   g      [+256)              label-sum vectors g0,g1 (fp32)
//   cnt    [+2)                label counts in y2
//   spart  [+64*N)             partial exp row-sums, slice-major [slice*N+row]
//   part   [+2048)             per-block loss partials
#define PNH_F     (NROW * DIM / 2)
#define PNSWB_OFF PNH_F
#define PNSWA_OFF (2 * PNH_F)
#define G_OFF     (3 * PNH_F)
#define CNT_OFF   (G_OFF + 256)
#define SPART_OFF (G_OFF + 512)
#define PART_OFF  (SPART_OFF + 64 * NROW)

__device__ __forceinline__ unsigned short f2bf(float f) {  // RNE
    unsigned u = __float_as_uint(f);
    return (unsigned short)((u + 0x7FFF + ((u >> 16) & 1)) >> 16);
}

// ------ Kernel 1: row normalization -> bf16 (wave per row) + zero g -------
// Emits pnh (linear), pnswB (swizzled), pnswA (swizzled, x LOG2E10 so the
// MFMA dot directly yields sim*10/ln2 -> epilogue is a bare exp2f).
__global__ void k_norm(const float* __restrict__ zi, const float* __restrict__ zj,
                       unsigned* __restrict__ pnh, unsigned* __restrict__ pnswB,
                       unsigned* __restrict__ pnswA, float* __restrict__ g) {
    int tid  = threadIdx.x;
    if (blockIdx.x == 0) g[tid] = 0.f;      // zero g before k_colsum's atomics
    int wave = tid >> 6, lane = tid & 63;
    int row  = blockIdx.x * 4 + wave;
    const float* src = (row < BSZ) ? (zi + (size_t)row * DIM)
                                   : (zj + (size_t)(row - BSZ) * DIM);
    float2 v = ((const float2*)src)[lane];
    float ss = v.x * v.x + v.y * v.y;
    #pragma unroll
    for (int m = 32; m; m >>= 1) ss += __shfl_xor(ss, m, 64);
    float inv = 1.0f / fmaxf(sqrtf(ss), 1e-8f);
    float n0 = v.x * inv, n1 = v.y * inv;
    unsigned pack  = (unsigned)f2bf(n0) | ((unsigned)f2bf(n1) << 16);
    unsigned packA = (unsigned)f2bf(n0 * LOG2E10) | ((unsigned)f2bf(n1 * LOG2E10) << 16);
    pnh[(size_t)row * 64 + lane] = pack;
    int j = lane >> 2;                       // 16B chunk index (4 uints each)
    int sw = ((j ^ (row & 15)) << 2) | (lane & 3);
    pnswB[(size_t)row * 64 + sw] = pack;
    pnswA[(size_t)row * 64 + sw] = packA;
}

// ---- Kernel 2: label-sum vectors g0/g1, coalesced row-major + atomics ----
__global__ void k_colsum(const unsigned* __restrict__ pnh, const int* __restrict__ y,
                         float* __restrict__ g, float* __restrict__ cnt) {
    __shared__ float red[4][4][64];   // [rowgrp][{s0a,s0b,s1a,s1b}][d2]
    int tid = threadIdx.x;
    if (blockIdx.x < 128) {
        int d2 = tid & 63;            // uint index: holds d = 2*d2, 2*d2+1
        int rg = tid >> 6;            // 0..3
        int row0 = blockIdx.x * 64 + rg * 16;
        float s0a = 0.f, s0b = 0.f, s1a = 0.f, s1b = 0.f;
        #pragma unroll 4
        for (int i = 0; i < 16; ++i) {
            int r = row0 + i;
            unsigned u = pnh[(size_t)r * 64 + d2];
            float va = __uint_as_float(u << 16);
            float vb = __uint_as_float(u & 0xFFFF0000u);
            if (y[r & (BSZ - 1)]) { s1a += va; s1b += vb; }
            else                  { s0a += va; s0b += vb; }
        }
        red[rg][0][d2] = s0a; red[rg][1][d2] = s0b;
        red[rg][2][d2] = s1a; red[rg][3][d2] = s1b;
        __syncthreads();
        int lab = tid >> 7, d = tid & 127;
        int which = lab * 2 + (d & 1), dd2 = d >> 1;
        float s = red[0][which][dd2] + red[1][which][dd2]
                + red[2][which][dd2] + red[3][which][dd2];
        atomicAdd(&g[lab * DIM + d], s);
    } else {
        __shared__ float r0[256];
        float c = 0.f;
        for (int r = tid; r < BSZ; r += 256) c += (float)y[r];
        r0[tid] = c;
        __syncthreads();
        for (int s = 128; s; s >>= 1) {
            if (tid < s) r0[tid] += r0[tid + s];
            __syncthreads();
        }
        if (tid == 0) { cnt[1] = 2.0f * r0[0]; cnt[0] = (float)NROW - 2.0f * r0[0]; }
    }
}

// ---- Kernel 3: SYMMETRIC bf16 MFMA exp-GEMM over the UPPER TRIANGLE ------
// sim is symmetric: exp(sim_ij)=exp(sim_ji). Only tiles (ti<=tj) are
// computed (2080 of 4096): each off-diag tile yields rs (rows of ti,
// reduce over cols -> slice tj) AND cs (rows of tj, reduce over rows ->
// slice ti). Slice coverage for (row-tile a, slice s): s>a rs of (a,s);
// s<a cs of (s,a); s==a rs of diag — exactly once each. ~2x less MFMA,
// exp, and loads than round 7.
// Block = 128x128 tile, 4 waves x (32 rows x 128 cols): a[2][4]=32 VGPR,
// total ~92 (round-8 lesson: M_w=64 all-reg spills past the 128 cap).
// B tile 32 KB LDS staged once; A pre-scaled so epilogue = exp2f only.
__global__ __launch_bounds__(256, 4)
void k_expsum(const unsigned short* __restrict__ pnswA,
              const unsigned short* __restrict__ pnswB,
              float* __restrict__ spart) {
    int ti = blockIdx.y, tj = blockIdx.x;
    if (tj < ti) return;                     // lower triangle: retire instantly
    __shared__ short bt[128 * 128];          // 32 KB B tile (rows of tile tj)
    __shared__ float rs_t[128];              // row sums of tile ti
    __shared__ float cs_p[4][128];           // per-wave col-sum partials
    int tid  = threadIdx.x;
    int lane = tid & 63;
    int w    = tid >> 6;
    int l15 = lane & 15, q = lane >> 4;
    bool isDiag = (ti == tj);
    int rwb = ti * 128 + w * 32;             // this wave's 32 rows

    // stage B tile: linear 32 KB copy (source pre-swizzled)
    {
        const float4* src = (const float4*)(pnswB + (size_t)tj * 128 * DIM);
        float4* dst = (float4*)bt;
        #pragma unroll
        for (int i = 0; i < 8; ++i)
            dst[tid + 256 * i] = src[tid + 256 * i];
    }

    // A fragments (scaled): lane holds A[m=l15][k=q*8+j], chunk (ks*4+q)^l15
    bf16x8 a[2][4];
    #pragma unroll
    for (int rf = 0; rf < 2; ++rf) {
        const unsigned short* ab = pnswA + (size_t)(rwb + rf * 16 + l15) * DIM;
        #pragma unroll
        for (int ks = 0; ks < 4; ++ks)
            a[rf][ks] = *(const bf16x8*)(ab + (((ks * 4 + q) ^ l15) << 3));
    }

    float rs[2][4], cs[8];
    #pragma unroll
    for (int rf = 0; rf < 2; ++rf)
        #pragma unroll
        for (int e = 0; e < 4; ++e) rs[rf][e] = 0.f;
    #pragma unroll
    for (int t = 0; t < 8; ++t) cs[t] = 0.f;

    __syncthreads();                         // B tile ready

    #pragma unroll
    for (int t = 0; t < 8; ++t) {            // 8 col-16 subtiles
        bf16x8 b[4];
        #pragma unroll
        for (int ks = 0; ks < 4; ++ks)
            b[ks] = *(const bf16x8*)(bt + (t * 16 + l15) * 128 + (((ks * 4 + q) ^ l15) << 3));

        f32x4 acc[2];
        acc[0] = (f32x4){0.f, 0.f, 0.f, 0.f};
        acc[1] = (f32x4){0.f, 0.f, 0.f, 0.f};
        #pragma unroll
        for (int ks = 0; ks < 4; ++ks) {
            acc[0] = __builtin_amdgcn_mfma_f32_16x16x32_bf16(a[0][ks], b[ks], acc[0], 0, 0, 0);
            acc[1] = __builtin_amdgcn_mfma_f32_16x16x32_bf16(a[1][ks], b[ks], acc[1], 0, 0, 0);
        }

        // epilogue: acc already = sim*10/ln2 (A pre-scaled) -> bare exp2f.
        // Diagonal masking only in the diag tile's overlapping subtiles.
        if (isDiag && ((unsigned)(t * 16 - w * 32) < 32u)) {
            int col = tj * 128 + t * 16 + l15;
            #pragma unroll
            for (int rf = 0; rf < 2; ++rf)
                #pragma unroll
                for (int e = 0; e < 4; ++e) {
                    int row = rwb + rf * 16 + q * 4 + e;   // C-layout row
                    float ex = exp2f(acc[rf][e]);
                    if (row == col) ex = 0.f;
                    rs[rf][e] += ex; cs[t] += ex;
                }
        } else {
            #pragma unroll
            for (int rf = 0; rf < 2; ++rf)
                #pragma unroll
                for (int e = 0; e < 4; ++e) {
                    float ex = exp2f(acc[rf][e]);
                    rs[rf][e] += ex; cs[t] += ex;
                }
        }
    }

    // rs: reduce over the 16 cols held across l15 lanes -> rs_t (per-wave
    // private 32-slot region, no races)
    #pragma unroll
    for (int rf = 0; rf < 2; ++rf)
        #pragma unroll
        for (int e = 0; e < 4; ++e) {
            float v = rs[rf][e];
            v += __shfl_xor(v, 1, 16);
            v += __shfl_xor(v, 2, 16);
            v += __shfl_xor(v, 4, 16);
            v += __shfl_xor(v, 8, 16);
            if (l15 == 0) rs_t[w * 32 + rf * 16 + q * 4 + e] = v;
        }
    // cs: reduce over the 4 quads (rows) -> lanes 0..15 hold col partials
    #pragma unroll
    for (int t = 0; t < 8; ++t) {
        float v = cs[t];
        v += __shfl_xor(v, 16, 64);
        v += __shfl_xor(v, 32, 64);
        if (q == 0) cs_p[w][t * 16 + l15] = v;
    }
    __syncthreads();

    // coalesced 512 B stores into block-private slice runs
    if (tid < 128) {
        spart[(size_t)tj * NROW + ti * 128 + tid] = rs_t[tid];
    } else if (!isDiag) {
        int c = tid - 128;
        float v = cs_p[0][c] + cs_p[1][c] + cs_p[2][c] + cs_p[3][c];
        spart[(size_t)ti * NROW + tj * 128 + c] = v;
    }
}

// ------------- Kernel 4: per-row finalize (wave per row, 2048 blocks) ------
__global__ void k_finalize(const unsigned* __restrict__ pnh, const float* __restrict__ spart,
                           const float* __restrict__ g, const float* __restrict__ cnt,
                           const int* __restrict__ y, float* __restrict__ partial) {
    __shared__ float red[4];
    int tid = threadIdx.x, wv = tid >> 6, lane = tid & 63;
    int row = blockIdx.x * 4 + wv;
    int lab = y[row & (BSZ - 1)];
    unsigned u = pnh[(size_t)row * 64 + lane];
    float p0 = __uint_as_float(u << 16);
    float p1 = __uint_as_float(u & 0xFFFF0000u);
    float2 gv = ((const float2*)(g + lab * DIM))[lane];
    float dg = p0 * gv.x + p1 * gv.y;
    float ds = p0 * p0 + p1 * p1;
    float sp = spart[(size_t)lane * NROW + row];   // lane = slice (L2-resident)
    #pragma unroll
    for (int m = 32; m; m >>= 1) {
        dg += __shfl_xor(dg, m, 64);
        ds += __shfl_xor(ds, m, 64);
        sp += __shfl_xor(sp, m, 64);
    }
    if (lane == 0) {
        float C = cnt[lab] - 1.0f;           // pos count excludes self
        float P = (dg - ds) * 10.0f;         // sum of sims over positives
        red[wv] = logf(sp) - P / C;          // -(mean log prob pos)
    }
    __syncthreads();
    if (tid == 0) partial[blockIdx.x] = red[0] + red[1] + red[2] + red[3];
}

// --------------------- Kernel 5: final reduce of 2048 ----------------------
__global__ void k_sum(const float* __restrict__ partial, float* __restrict__ out) {
    __shared__ float red[256];
    float v = 0.f;
    #pragma unroll
    for (int i = 0; i < 8; ++i) v += partial[threadIdx.x + 256 * i];
    red[threadIdx.x] = v;
    __syncthreads();
    for (int s = 128; s; s >>= 1) {
        if (threadIdx.x < s) red[threadIdx.x] += red[threadIdx.x + s];
        __syncthreads();
    }
    if (threadIdx.x == 0) out[0] = red[0];
}

extern "C" void kernel_launch(void* const* d_in, const int* in_sizes, int n_in,
                              void* d_out, int out_size, void* d_ws, size_t ws_size,
                              hipStream_t stream) {
    const float* zi = (const float*)d_in[0];
    const float* zj = (const float*)d_in[1];
    const int*   y  = (const int*)d_in[2];
    float* out = (float*)d_out;
    float* ws  = (float*)d_ws;

    unsigned* pnh   = (unsigned*)ws;                     // linear
    unsigned* pnswB = (unsigned*)(ws + PNSWB_OFF);       // swizzled
    unsigned* pnswA = (unsigned*)(ws + PNSWA_OFF);       // swizzled, x10/ln2
    float* g       = ws + G_OFF;
    float* cnt     = ws + CNT_OFF;
    float* spart   = ws + SPART_OFF;
    float* partial = ws + PART_OFF;

    k_norm<<<NROW / 4, 256, 0, stream>>>(zi, zj, pnh, pnswB, pnswA, g);
    k_colsum<<<129, 256, 0, stream>>>(pnh, y, g, cnt);
    k_expsum<<<dim3(64, 64), 256, 0, stream>>>((const unsigned short*)pnswA,
                                               (const unsigned short*)pnswB, spart);
    k_finalize<<<NROW / 4, 256, 0, stream>>>(pnh, spart, g, cnt, y, partial);
    k_sum<<<1, 256, 0, stream>>>(partial, out);
}